// Round 9
// baseline (156.402 us; speedup 1.0000x reference)
//
#include <hip/hip_runtime.h>
#include <math.h>

#define N_NODES 50000
#define N_EDGES 800000
#define IN_DIM 128
#define N_HEADS 4
#define OUT_DIM 32
#define PROJ_DIM 128   // N_HEADS * OUT_DIM
#define CAP 48         // bucket capacity; max degree ~38 for Poisson(16)
#define WSTR 144       // Wt LDS row stride in shorts (288 B, 16B-aligned)
#define DEGS 16        // deg stride in ints: 1 counter per 64B line
                       // (800k same-line atomics serialized by cross-XCD line
                       //  migration was the invariant ~50us; 16 counters/line
                       //  -> 256 atomics/line. Padding cuts density 16x.)

#define PROJ_BLKS 391                    // ceil(50000/128), 128 rows/block
#define BUCKET_BLKS 1563                 // ceil(800000/512), 2 edges/thread
#define TOTAL_BLKS (PROJ_BLKS + BUCKET_BLKS)

typedef short bf16x8 __attribute__((ext_vector_type(8)));
typedef float f32x4  __attribute__((ext_vector_type(4)));
typedef _Float16 h2  __attribute__((ext_vector_type(2)));

// fp32 -> bf16 bits with round-to-nearest-even
__device__ __forceinline__ ushort f32_to_bf16(float f) {
    unsigned u = __float_as_uint(f);
    unsigned r = u + 0x7fffu + ((u >> 16) & 1u);
    return (ushort)(r >> 16);
}

__device__ __forceinline__ float bf16_to_f32(ushort v) {
    return __uint_as_float((unsigned)v << 16);
}

__device__ __forceinline__ bf16x8 cvt8(float4 a, float4 b) {
    bf16x8 r;
    r[0] = (short)f32_to_bf16(a.x); r[1] = (short)f32_to_bf16(a.y);
    r[2] = (short)f32_to_bf16(a.z); r[3] = (short)f32_to_bf16(a.w);
    r[4] = (short)f32_to_bf16(b.x); r[5] = (short)f32_to_bf16(b.y);
    r[6] = (short)f32_to_bf16(b.z); r[7] = (short)f32_to_bf16(b.w);
    return r;
}

// ---------------------------------------------------------------------------
// K1: BLOCK-SPECIALIZED combo (proj MFMA blocks + bucket blocks co-resident).
// ---------------------------------------------------------------------------
__global__ __launch_bounds__(256) void combo_kernel(
    const float* __restrict__ X, const float* __restrict__ W,
    const float* __restrict__ att, const int* __restrict__ ei,
    ushort* __restrict__ projT, float* __restrict__ s_src, float* __restrict__ s_tgt,
    int* __restrict__ deg, ushort* __restrict__ bucket)
{
    __shared__ ushort Wt[128 * WSTR];   // 36.9 KB: Wt[col][k] bf16

    const int tid = threadIdx.x;

    if (blockIdx.x >= PROJ_BLKS) {
        // ---------------- bucket part: 2 edges per thread ----------------
        int b2 = blockIdx.x - PROJ_BLKS;
        int e0 = b2 * 512 + tid;
#pragma unroll
        for (int i = 0; i < 2; ++i) {
            int e = e0 + i * 256;
            if (e < N_EDGES) {
                int src = ei[e];
                int tgt = ei[N_EDGES + e];
                int pos = atomicAdd(&deg[src * DEGS], 1);   // padded: 1 ctr/line
                if (pos < CAP)
                    __builtin_nontemporal_store((ushort)tgt, &bucket[src * CAP + pos]);
            }
        }
        return;
    }

    // ------------------------- proj part ---------------------------------
    // stage W transposed as bf16: Wt[c][k], k packed in pairs (b32 writes)
    for (int idx = tid; idx < 64 * 128; idx += 256) {
        int kp = idx >> 7;          // k-pair 0..63
        int c  = idx & 127;
        float w0 = W[(2 * kp) * PROJ_DIM + c];       // coalesced across lanes
        float w1 = W[(2 * kp + 1) * PROJ_DIM + c];
        unsigned pr = (unsigned)f32_to_bf16(w0) | ((unsigned)f32_to_bf16(w1) << 16);
        *(unsigned*)&Wt[c * WSTR + 2 * kp] = pr;
    }
    __syncthreads();

    const int wv   = tid >> 6;         // wave 0..3
    const int lane = tid & 63;
    const int m = lane & 15;           // A row within tile / B col within tile
    const int q = lane >> 4;           // quad
    const int rbase = blockIdx.x * 128;

    int arow0 = rbase + wv * 32 + m;
    int arow1 = arow0 + 16;
    arow0 = (arow0 < N_NODES) ? arow0 : N_NODES - 1;
    arow1 = (arow1 < N_NODES) ? arow1 : N_NODES - 1;
    const long long xb0 = (long long)arow0 * IN_DIM;
    const long long xb1 = (long long)arow1 * IN_DIM;

    f32x4 acc[2][8];
#pragma unroll
    for (int rt = 0; rt < 2; ++rt)
#pragma unroll
        for (int ct = 0; ct < 8; ++ct) acc[rt][ct] = (f32x4){0.f, 0.f, 0.f, 0.f};

#pragma unroll
    for (int ks = 0; ks < 4; ++ks) {
        const int k0 = ks * 32 + q * 8;
        float4 a0lo = *(const float4*)&X[xb0 + k0];
        float4 a0hi = *(const float4*)&X[xb0 + k0 + 4];
        float4 a1lo = *(const float4*)&X[xb1 + k0];
        float4 a1hi = *(const float4*)&X[xb1 + k0 + 4];
        bf16x8 afrag0 = cvt8(a0lo, a0hi);
        bf16x8 afrag1 = cvt8(a1lo, a1hi);
#pragma unroll
        for (int ct = 0; ct < 8; ++ct) {
            bf16x8 bfrag = *(const bf16x8*)&Wt[(ct * 16 + m) * WSTR + k0];
            acc[0][ct] = __builtin_amdgcn_mfma_f32_16x16x32_bf16(afrag0, bfrag, acc[0][ct], 0, 0, 0);
            acc[1][ct] = __builtin_amdgcn_mfma_f32_16x16x32_bf16(afrag1, bfrag, acc[1][ct], 0, 0, 0);
        }
    }

    // Epilogue: col = ct*16 + m; h = ct>>1; d = (ct&1)*16 + m.
    const float as_lo = att[m],      as_hi = att[m + 16];
    const float at_lo = att[32 + m], at_hi = att[48 + m];

#pragma unroll
    for (int rt = 0; rt < 2; ++rt) {
        const int rowb = rbase + wv * 32 + rt * 16 + q * 4;
#pragma unroll
        for (int r = 0; r < 4; ++r) {
            const int row = rowb + r;
            float cl[4], ch[4];
#pragma unroll
            for (int h = 0; h < 4; ++h) {
                cl[h] = acc[rt][2 * h][r];
                ch[h] = acc[rt][2 * h + 1][r];
            }
            if (row < N_NODES) {
                ushort4 plo, phi;
                plo.x = f32_to_bf16(cl[0]); plo.y = f32_to_bf16(cl[1]);
                plo.z = f32_to_bf16(cl[2]); plo.w = f32_to_bf16(cl[3]);
                phi.x = f32_to_bf16(ch[0]); phi.y = f32_to_bf16(ch[1]);
                phi.z = f32_to_bf16(ch[2]); phi.w = f32_to_bf16(ch[3]);
                *(ushort4*)&projT[(long long)row * PROJ_DIM + m * 4] = plo;
                *(ushort4*)&projT[(long long)row * PROJ_DIM + (m + 16) * 4] = phi;
            }
            float ps[4], pt[4];
#pragma unroll
            for (int h = 0; h < 4; ++h) {
                ps[h] = cl[h] * as_lo + ch[h] * as_hi;
                pt[h] = cl[h] * at_lo + ch[h] * at_hi;
            }
#pragma unroll
            for (int off = 8; off > 0; off >>= 1) {
#pragma unroll
                for (int h = 0; h < 4; ++h) {
                    ps[h] += __shfl_down(ps[h], off, 16);
                    pt[h] += __shfl_down(pt[h], off, 16);
                }
            }
            if (m == 0 && row < N_NODES) {
                *(float4*)&s_src[row * N_HEADS] = make_float4(ps[0], ps[1], ps[2], ps[3]);
                *(float4*)&s_tgt[row * N_HEADS] = make_float4(pt[0], pt[1], pt[2], pt[3]);
            }
        }
    }
}

// ---------------------------------------------------------------------------
// K2: gather. One WAVE per node; lane=edge softmax prep in LDS, then x8
// unrolled accumulate per half-wave (8 independent ds_read_b128 + 8
// independent 8B projT gathers in flight).
// ---------------------------------------------------------------------------
__global__ __launch_bounds__(256) void gather_kernel(
    const int* __restrict__ deg, const ushort* __restrict__ bucket,
    const float* __restrict__ s_src, const float* __restrict__ s_tgt,
    const ushort* __restrict__ projT, float* __restrict__ out)
{
    __shared__ int4 es[4][CAP];        // 3 KB

    const int wv   = threadIdx.x >> 6;     // wave in block: 0..3
    const int lane = threadIdx.x & 63;
    const int node = blockIdx.x * 4 + wv;  // N_NODES = 12500*4, always valid

    int n = deg[node * DEGS];
    n = (n < CAP) ? n : CAP;

    if (lane < n) {
        int tgt = bucket[node * CAP + lane];                // coalesced ushort
        float4 ss = *(const float4*)&s_src[node * N_HEADS]; // broadcast
        float4 st = *(const float4*)&s_tgt[tgt * N_HEADS];  // parallel gather

        float sc[4] = { ss.x + st.x, ss.y + st.y, ss.z + st.z, ss.w + st.w };
        float mx = -1e30f;
#pragma unroll
        for (int h = 0; h < 4; ++h) {
            sc[h] = (sc[h] > 0.0f) ? sc[h] : 0.01f * sc[h];  // leaky_relu
            mx = fmaxf(mx, sc[h]);
        }
        float sum = 0.0f;
#pragma unroll
        for (int h = 0; h < 4; ++h) {
            sc[h] = __expf(sc[h] - mx);
            sum += sc[h];
        }
        float inv = 0.25f / sum;     // softmax normalize * head-mean

        h2 a01, a23;
        a01.x = (_Float16)(sc[0] * inv);
        a01.y = (_Float16)(sc[1] * inv);
        a23.x = (_Float16)(sc[2] * inv);
        a23.y = (_Float16)(sc[3] * inv);
        es[wv][lane] = make_int4(tgt, __builtin_bit_cast(int, a01),
                                      __builtin_bit_cast(int, a23), 0);
    }
    __syncthreads();   // block-uniform

    const int d    = lane & 31;
    const int half = lane >> 5;

    float acc0 = 0.0f, acc1 = 0.0f, acc2 = 0.0f, acc3 = 0.0f;
    int j = half;

    // 8 edges per half-wave per pass -> 8 outstanding gathers
    for (; j + 14 < n; j += 16) {
        int4 e[8];
        ushort4 p[8];
#pragma unroll
        for (int u = 0; u < 8; ++u) e[u] = es[wv][j + 2 * u];
#pragma unroll
        for (int u = 0; u < 8; ++u)
            p[u] = *(const ushort4*)&projT[(long long)e[u].x * PROJ_DIM + d * 4];
#pragma unroll
        for (int u = 0; u < 8; ++u) {
            h2 a = __builtin_bit_cast(h2, e[u].y);
            h2 b = __builtin_bit_cast(h2, e[u].z);
            float* accp = (u & 1) ? ((u & 2) ? &acc3 : &acc1)
                                  : ((u & 2) ? &acc2 : &acc0);
            float t = *accp;
            t = fmaf((float)a.x, bf16_to_f32(p[u].x), t);
            t = fmaf((float)a.y, bf16_to_f32(p[u].y), t);
            t = fmaf((float)b.x, bf16_to_f32(p[u].z), t);
            t = fmaf((float)b.y, bf16_to_f32(p[u].w), t);
            *accp = t;
        }
    }
    // remainder: 2-stride pairs
    for (; j < n; j += 2) {
        int4 e4 = es[wv][j];
        ushort4 pv = *(const ushort4*)&projT[(long long)e4.x * PROJ_DIM + d * 4];
        h2 a01 = __builtin_bit_cast(h2, e4.y);
        h2 a23 = __builtin_bit_cast(h2, e4.z);
        acc0 = fmaf((float)a01.x, bf16_to_f32(pv.x), acc0);
        acc0 = fmaf((float)a01.y, bf16_to_f32(pv.y), acc0);
        acc0 = fmaf((float)a23.x, bf16_to_f32(pv.z), acc0);
        acc0 = fmaf((float)a23.y, bf16_to_f32(pv.w), acc0);
    }

    float acc = (acc0 + acc1) + (acc2 + acc3);
    acc += __shfl_down(acc, 32);      // combine the two halves (width 64)
    if (lane < 32) out[node * OUT_DIM + d] = acc;
}

extern "C" void kernel_launch(void* const* d_in, const int* in_sizes, int n_in,
                              void* d_out, int out_size, void* d_ws, size_t ws_size,
                              hipStream_t stream) {
    const float* X   = (const float*)d_in[0];
    const int*   ei  = (const int*)d_in[1];
    const float* W   = (const float*)d_in[2];
    const float* att = (const float*)d_in[3];
    float* out = (float*)d_out;

    // workspace layout, total ~22.4 MB
    char* p = (char*)d_ws;
    ushort* projT  = (ushort*)p; p += (size_t)N_NODES * PROJ_DIM * 2;   // 12.8 MB
    float* s_src   = (float*)p;  p += (size_t)N_NODES * N_HEADS * 4;    // 0.8 MB
    float* s_tgt   = (float*)p;  p += (size_t)N_NODES * N_HEADS * 4;    // 0.8 MB
    int* deg       = (int*)p;    p += (size_t)N_NODES * DEGS * 4;       // 3.2 MB (padded)
    ushort* bucket = (ushort*)p; p += (size_t)N_NODES * CAP * 2;        // 4.8 MB

    (void)hipMemsetAsync(deg, 0, (size_t)N_NODES * DEGS * sizeof(int), stream);

    combo_kernel<<<TOTAL_BLKS, 256, 0, stream>>>(
        X, W, att, ei, projT, s_src, s_tgt, deg, bucket);

    gather_kernel<<<N_NODES / 4, 256, 0, stream>>>(
        deg, bucket, s_src, s_tgt, projT, out);
}

// Round 10
// 146.848 us; speedup vs baseline: 1.0651x; 1.0651x over previous
//
#include <hip/hip_runtime.h>
#include <math.h>

#define N_NODES 50000
#define N_EDGES 800000
#define IN_DIM 128
#define N_HEADS 4
#define OUT_DIM 32
#define PROJ_DIM 128   // N_HEADS * OUT_DIM
#define WSTR 144       // Wt LDS row stride in shorts (288 B, 16B-aligned)

#define NBIN 196       // ceil(50000/256): bin = src >> 8
#define BINCAP 5000    // edges per bin region (mean 4096, sigma ~64 -> 14 sigma)
#define MAXDEG 64      // gather clamp (max expected deg ~38 for Poisson(16))

#define PROJ_BLKS 391                    // ceil(50000/128), 128 rows/block
#define PART_BLKS 391                    // 2048 edges per block
#define TOTAL_BLKS (PROJ_BLKS + PART_BLKS)

typedef short bf16x8 __attribute__((ext_vector_type(8)));
typedef float f32x4  __attribute__((ext_vector_type(4)));
typedef _Float16 h2  __attribute__((ext_vector_type(2)));

// fp32 -> bf16 bits with round-to-nearest-even
__device__ __forceinline__ ushort f32_to_bf16(float f) {
    unsigned u = __float_as_uint(f);
    unsigned r = u + 0x7fffu + ((u >> 16) & 1u);
    return (ushort)(r >> 16);
}

__device__ __forceinline__ float bf16_to_f32(ushort v) {
    return __uint_as_float((unsigned)v << 16);
}

__device__ __forceinline__ bf16x8 cvt8(float4 a, float4 b) {
    bf16x8 r;
    r[0] = (short)f32_to_bf16(a.x); r[1] = (short)f32_to_bf16(a.y);
    r[2] = (short)f32_to_bf16(a.z); r[3] = (short)f32_to_bf16(a.w);
    r[4] = (short)f32_to_bf16(b.x); r[5] = (short)f32_to_bf16(b.y);
    r[6] = (short)f32_to_bf16(b.z); r[7] = (short)f32_to_bf16(b.w);
    return r;
}

// ---------------------------------------------------------------------------
// K1: BLOCK-SPECIALIZED combo.
//  blocks [0,PROJ_BLKS): proj = X @ W via bf16 MFMA 16x16x32 (as R8).
//  blocks [PROJ_BLKS,..): EDGE PARTITION into 196 coarse bins (src>>8).
//    2048 edges/block: LDS histogram (LDS returning atomics, CU-local),
//    ONE global returning atomic per (block,bin) to reserve slots (77k total
//    vs 800k per-edge — the measured wall was ~6.5 returning atomics/cycle
//    chip-wide), then plain packed stores (tgt<<16 | src&255).
// ---------------------------------------------------------------------------
__global__ __launch_bounds__(256) void combo_kernel(
    const float* __restrict__ X, const float* __restrict__ W,
    const float* __restrict__ att, const int* __restrict__ ei,
    ushort* __restrict__ projT, float* __restrict__ s_src, float* __restrict__ s_tgt,
    int* __restrict__ bin_cursor, unsigned* __restrict__ slab)
{
    __shared__ ushort Wt[128 * WSTR];   // 36.9 KB (partition blocks alias it)

    const int tid = threadIdx.x;

    if (blockIdx.x >= PROJ_BLKS) {
        // ---------------- partition part: 2048 edges per block -----------
        int* cnt   = (int*)Wt;          // 196 ints (aliased onto Wt storage)
        int* gbase = cnt + 256;         // 196 ints

        for (int t = tid; t < NBIN; t += 256) cnt[t] = 0;
        __syncthreads();

        const int ebase = (blockIdx.x - PROJ_BLKS) * 2048;
        unsigned srcv[8], tgtv[8];
        int rank[8];
#pragma unroll
        for (int i = 0; i < 8; ++i) {
            int e = ebase + i * 256 + tid;
            bool ok = e < N_EDGES;
            srcv[i] = ok ? (unsigned)ei[e] : 0u;
            tgtv[i] = ok ? (unsigned)ei[N_EDGES + e] : 0u;
            rank[i] = ok ? atomicAdd(&cnt[srcv[i] >> 8], 1) : -1;
        }
        __syncthreads();

        for (int t = tid; t < NBIN; t += 256)
            gbase[t] = atomicAdd(&bin_cursor[t], cnt[t]);   // 196/block global
        __syncthreads();

#pragma unroll
        for (int i = 0; i < 8; ++i) {
            if (rank[i] >= 0) {
                int bin = srcv[i] >> 8;
                int p = gbase[bin] + rank[i];
                if (p < BINCAP)
                    slab[bin * BINCAP + p] = (tgtv[i] << 16) | (srcv[i] & 255u);
            }
        }
        return;
    }

    // ------------------------- proj part (unchanged R8) -------------------
    for (int idx = tid; idx < 64 * 128; idx += 256) {
        int kp = idx >> 7;
        int c  = idx & 127;
        float w0 = W[(2 * kp) * PROJ_DIM + c];
        float w1 = W[(2 * kp + 1) * PROJ_DIM + c];
        unsigned pr = (unsigned)f32_to_bf16(w0) | ((unsigned)f32_to_bf16(w1) << 16);
        *(unsigned*)&Wt[c * WSTR + 2 * kp] = pr;
    }
    __syncthreads();

    const int wv   = tid >> 6;
    const int lane = tid & 63;
    const int m = lane & 15;
    const int q = lane >> 4;
    const int rbase = blockIdx.x * 128;

    int arow0 = rbase + wv * 32 + m;
    int arow1 = arow0 + 16;
    arow0 = (arow0 < N_NODES) ? arow0 : N_NODES - 1;
    arow1 = (arow1 < N_NODES) ? arow1 : N_NODES - 1;
    const long long xb0 = (long long)arow0 * IN_DIM;
    const long long xb1 = (long long)arow1 * IN_DIM;

    f32x4 acc[2][8];
#pragma unroll
    for (int rt = 0; rt < 2; ++rt)
#pragma unroll
        for (int ct = 0; ct < 8; ++ct) acc[rt][ct] = (f32x4){0.f, 0.f, 0.f, 0.f};

#pragma unroll
    for (int ks = 0; ks < 4; ++ks) {
        const int k0 = ks * 32 + q * 8;
        float4 a0lo = *(const float4*)&X[xb0 + k0];
        float4 a0hi = *(const float4*)&X[xb0 + k0 + 4];
        float4 a1lo = *(const float4*)&X[xb1 + k0];
        float4 a1hi = *(const float4*)&X[xb1 + k0 + 4];
        bf16x8 afrag0 = cvt8(a0lo, a0hi);
        bf16x8 afrag1 = cvt8(a1lo, a1hi);
#pragma unroll
        for (int ct = 0; ct < 8; ++ct) {
            bf16x8 bfrag = *(const bf16x8*)&Wt[(ct * 16 + m) * WSTR + k0];
            acc[0][ct] = __builtin_amdgcn_mfma_f32_16x16x32_bf16(afrag0, bfrag, acc[0][ct], 0, 0, 0);
            acc[1][ct] = __builtin_amdgcn_mfma_f32_16x16x32_bf16(afrag1, bfrag, acc[1][ct], 0, 0, 0);
        }
    }

    const float as_lo = att[m],      as_hi = att[m + 16];
    const float at_lo = att[32 + m], at_hi = att[48 + m];

#pragma unroll
    for (int rt = 0; rt < 2; ++rt) {
        const int rowb = rbase + wv * 32 + rt * 16 + q * 4;
#pragma unroll
        for (int r = 0; r < 4; ++r) {
            const int row = rowb + r;
            float cl[4], ch[4];
#pragma unroll
            for (int h = 0; h < 4; ++h) {
                cl[h] = acc[rt][2 * h][r];
                ch[h] = acc[rt][2 * h + 1][r];
            }
            if (row < N_NODES) {
                ushort4 plo, phi;
                plo.x = f32_to_bf16(cl[0]); plo.y = f32_to_bf16(cl[1]);
                plo.z = f32_to_bf16(cl[2]); plo.w = f32_to_bf16(cl[3]);
                phi.x = f32_to_bf16(ch[0]); phi.y = f32_to_bf16(ch[1]);
                phi.z = f32_to_bf16(ch[2]); phi.w = f32_to_bf16(ch[3]);
                *(ushort4*)&projT[(long long)row * PROJ_DIM + m * 4] = plo;
                *(ushort4*)&projT[(long long)row * PROJ_DIM + (m + 16) * 4] = phi;
            }
            float ps[4], pt[4];
#pragma unroll
            for (int h = 0; h < 4; ++h) {
                ps[h] = cl[h] * as_lo + ch[h] * as_hi;
                pt[h] = cl[h] * at_lo + ch[h] * at_hi;
            }
#pragma unroll
            for (int off = 8; off > 0; off >>= 1) {
#pragma unroll
                for (int h = 0; h < 4; ++h) {
                    ps[h] += __shfl_down(ps[h], off, 16);
                    pt[h] += __shfl_down(pt[h], off, 16);
                }
            }
            if (m == 0 && row < N_NODES) {
                *(float4*)&s_src[row * N_HEADS] = make_float4(ps[0], ps[1], ps[2], ps[3]);
                *(float4*)&s_tgt[row * N_HEADS] = make_float4(pt[0], pt[1], pt[2], pt[3]);
            }
        }
    }
}

// ---------------------------------------------------------------------------
// K2: binsort. One block per bin (196 blocks, 256 threads). LDS-only atomics:
// count per node (256 bins), Hillis-Steele scan, scatter into LDS staging,
// coalesced dump to exact CSR + per-node offs/deg. Zero global atomics.
// ---------------------------------------------------------------------------
__global__ __launch_bounds__(256) void binsort_kernel(
    const unsigned* __restrict__ slab, const int* __restrict__ bin_cursor,
    ushort* __restrict__ csr, int* __restrict__ offs, int* __restrict__ deg)
{
    __shared__ int cnt2[256];
    __shared__ int pref[256];
    __shared__ int ex[256];
    __shared__ ushort stgt[BINCAP];    // 10 KB

    const int b = blockIdx.x;
    const int t = threadIdx.x;
    int n_e = bin_cursor[b];
    n_e = (n_e < BINCAP) ? n_e : BINCAP;

    cnt2[t] = 0;
    __syncthreads();

    // pass 1: read packed edges, rank per node via LDS atomics
    unsigned pk[20];                   // (tgt<<16)|(rank<<8)|node8
    int npk = 0;
    for (int i = t; i < n_e; i += 256) {
        unsigned v = slab[b * BINCAP + i];
        int node8 = v & 255u;
        int r = atomicAdd(&cnt2[node8], 1);
        r = (r < 255) ? r : 255;
        pk[npk++] = (v & 0xFFFF0000u) | ((unsigned)r << 8) | (unsigned)node8;
    }
    __syncthreads();

    // inclusive scan of cnt2 -> pref, then exclusive in ex
    pref[t] = cnt2[t];
    __syncthreads();
    for (int off = 1; off < 256; off <<= 1) {
        int x = (t >= off) ? pref[t - off] : 0;
        __syncthreads();
        pref[t] += x;
        __syncthreads();
    }
    ex[t] = pref[t] - cnt2[t];
    __syncthreads();

    // pass 2: scatter tgt into LDS by exact in-bin position
    for (int j = 0; j < npk; ++j) {
        unsigned v = pk[j];
        int lpos = ex[v & 255u] + (int)((v >> 8) & 255u);
        if (lpos < BINCAP) stgt[lpos] = (ushort)(v >> 16);
    }
    __syncthreads();

    // dump CSR coalesced + per-node metadata
    for (int i = t; i < n_e; i += 256) csr[b * BINCAP + i] = stgt[i];
    int node = b * 256 + t;
    if (node < N_NODES) {
        offs[node] = b * BINCAP + ex[t];
        deg[node]  = cnt2[t];
    }
}

// ---------------------------------------------------------------------------
// K3: gather. One WAVE per node; lane=edge softmax prep in LDS, then x8
// unrolled accumulate per half-wave (8 independent gathers in flight).
// ---------------------------------------------------------------------------
__global__ __launch_bounds__(256) void gather_kernel(
    const int* __restrict__ deg, const int* __restrict__ offs,
    const ushort* __restrict__ csr,
    const float* __restrict__ s_src, const float* __restrict__ s_tgt,
    const ushort* __restrict__ projT, float* __restrict__ out)
{
    __shared__ int4 es[4][MAXDEG];     // 4 KB

    const int wv   = threadIdx.x >> 6;
    const int lane = threadIdx.x & 63;
    const int node = blockIdx.x * 4 + wv;  // N_NODES = 12500*4

    int n = deg[node];
    n = (n < MAXDEG) ? n : MAXDEG;
    int o = offs[node];

    if (lane < n) {
        int tgt = csr[o + lane];                            // coalesced ushort
        float4 ss = *(const float4*)&s_src[node * N_HEADS]; // broadcast
        float4 st = *(const float4*)&s_tgt[tgt * N_HEADS];  // parallel gather

        float sc[4] = { ss.x + st.x, ss.y + st.y, ss.z + st.z, ss.w + st.w };
        float mx = -1e30f;
#pragma unroll
        for (int h = 0; h < 4; ++h) {
            sc[h] = (sc[h] > 0.0f) ? sc[h] : 0.01f * sc[h];  // leaky_relu
            mx = fmaxf(mx, sc[h]);
        }
        float sum = 0.0f;
#pragma unroll
        for (int h = 0; h < 4; ++h) {
            sc[h] = __expf(sc[h] - mx);
            sum += sc[h];
        }
        float inv = 0.25f / sum;     // softmax normalize * head-mean

        h2 a01, a23;
        a01.x = (_Float16)(sc[0] * inv);
        a01.y = (_Float16)(sc[1] * inv);
        a23.x = (_Float16)(sc[2] * inv);
        a23.y = (_Float16)(sc[3] * inv);
        es[wv][lane] = make_int4(tgt, __builtin_bit_cast(int, a01),
                                      __builtin_bit_cast(int, a23), 0);
    }
    __syncthreads();   // block-uniform

    const int d    = lane & 31;
    const int half = lane >> 5;

    float acc0 = 0.0f, acc1 = 0.0f, acc2 = 0.0f, acc3 = 0.0f;
    int j = half;

    for (; j + 14 < n; j += 16) {
        int4 e[8];
        ushort4 p[8];
#pragma unroll
        for (int u = 0; u < 8; ++u) e[u] = es[wv][j + 2 * u];
#pragma unroll
        for (int u = 0; u < 8; ++u)
            p[u] = *(const ushort4*)&projT[(long long)e[u].x * PROJ_DIM + d * 4];
#pragma unroll
        for (int u = 0; u < 8; ++u) {
            h2 a = __builtin_bit_cast(h2, e[u].y);
            h2 b = __builtin_bit_cast(h2, e[u].z);
            float* accp = (u & 1) ? ((u & 2) ? &acc3 : &acc1)
                                  : ((u & 2) ? &acc2 : &acc0);
            float tt = *accp;
            tt = fmaf((float)a.x, bf16_to_f32(p[u].x), tt);
            tt = fmaf((float)a.y, bf16_to_f32(p[u].y), tt);
            tt = fmaf((float)b.x, bf16_to_f32(p[u].z), tt);
            tt = fmaf((float)b.y, bf16_to_f32(p[u].w), tt);
            *accp = tt;
        }
    }
    for (; j < n; j += 2) {
        int4 e4 = es[wv][j];
        ushort4 pv = *(const ushort4*)&projT[(long long)e4.x * PROJ_DIM + d * 4];
        h2 a01 = __builtin_bit_cast(h2, e4.y);
        h2 a23 = __builtin_bit_cast(h2, e4.z);
        acc0 = fmaf((float)a01.x, bf16_to_f32(pv.x), acc0);
        acc0 = fmaf((float)a01.y, bf16_to_f32(pv.y), acc0);
        acc0 = fmaf((float)a23.x, bf16_to_f32(pv.z), acc0);
        acc0 = fmaf((float)a23.y, bf16_to_f32(pv.w), acc0);
    }

    float acc = (acc0 + acc1) + (acc2 + acc3);
    acc += __shfl_down(acc, 32);
    if (lane < 32) out[node * OUT_DIM + d] = acc;
}

extern "C" void kernel_launch(void* const* d_in, const int* in_sizes, int n_in,
                              void* d_out, int out_size, void* d_ws, size_t ws_size,
                              hipStream_t stream) {
    const float* X   = (const float*)d_in[0];
    const int*   ei  = (const int*)d_in[1];
    const float* W   = (const float*)d_in[2];
    const float* att = (const float*)d_in[3];
    float* out = (float*)d_out;

    // workspace layout, total ~20.8 MB
    char* p = (char*)d_ws;
    ushort* projT   = (ushort*)p;   p += (size_t)N_NODES * PROJ_DIM * 2;  // 12.8 MB
    float* s_src    = (float*)p;    p += (size_t)N_NODES * N_HEADS * 4;   // 0.8 MB
    float* s_tgt    = (float*)p;    p += (size_t)N_NODES * N_HEADS * 4;   // 0.8 MB
    unsigned* slab  = (unsigned*)p; p += (size_t)NBIN * BINCAP * 4;       // 3.92 MB
    ushort* csr     = (ushort*)p;   p += (size_t)NBIN * BINCAP * 2;       // 1.96 MB
    int* offs       = (int*)p;      p += (size_t)N_NODES * 4;             // 0.2 MB
    int* deg        = (int*)p;      p += (size_t)N_NODES * 4;             // 0.2 MB
    int* bin_cursor = (int*)p;      p += 256 * 4;

    (void)hipMemsetAsync(bin_cursor, 0, 256 * sizeof(int), stream);

    combo_kernel<<<TOTAL_BLKS, 256, 0, stream>>>(
        X, W, att, ei, projT, s_src, s_tgt, bin_cursor, slab);

    binsort_kernel<<<NBIN, 256, 0, stream>>>(slab, bin_cursor, csr, offs, deg);

    gather_kernel<<<N_NODES / 4, 256, 0, stream>>>(
        deg, offs, csr, s_src, s_tgt, projT, out);
}

// Round 13
// 145.479 us; speedup vs baseline: 1.0751x; 1.0094x over previous
//
#include <hip/hip_runtime.h>
#include <math.h>

#define N_NODES 50000
#define N_EDGES 800000
#define IN_DIM 128
#define N_HEADS 4
#define OUT_DIM 32
#define PROJ_DIM 128   // N_HEADS * OUT_DIM
#define WSTR 144       // Wt LDS row stride in shorts (288 B, 16B-aligned)

#define NBIN 196       // ceil(50000/256): bin = src >> 8
#define BINCAP 5000    // edges per bin region (mean 4096, sigma ~64 -> 14 sigma)
#define MAXDEG 64      // gather clamp (max expected deg ~38 for Poisson(16))

#define PROJ_BLKS 391                    // ceil(50000/128), 128 rows/block
#define PART_BLKS 391                    // 2048 edges per block
#define TOTAL_BLKS (PROJ_BLKS + PART_BLKS)

typedef short bf16x8 __attribute__((ext_vector_type(8)));
typedef float f32x4  __attribute__((ext_vector_type(4)));
typedef _Float16 h2  __attribute__((ext_vector_type(2)));

// fp32 -> bf16 bits with round-to-nearest-even
__device__ __forceinline__ ushort f32_to_bf16(float f) {
    unsigned u = __float_as_uint(f);
    unsigned r = u + 0x7fffu + ((u >> 16) & 1u);
    return (ushort)(r >> 16);
}

__device__ __forceinline__ float bf16_to_f32(ushort v) {
    return __uint_as_float((unsigned)v << 16);
}

__device__ __forceinline__ bf16x8 cvt8(float4 a, float4 b) {
    bf16x8 r;
    r[0] = (short)f32_to_bf16(a.x); r[1] = (short)f32_to_bf16(a.y);
    r[2] = (short)f32_to_bf16(a.z); r[3] = (short)f32_to_bf16(a.w);
    r[4] = (short)f32_to_bf16(b.x); r[5] = (short)f32_to_bf16(b.y);
    r[6] = (short)f32_to_bf16(b.z); r[7] = (short)f32_to_bf16(b.w);
    return r;
}

// ---------------------------------------------------------------------------
// K1: BLOCK-SPECIALIZED combo (unchanged from R10).
//  blocks [0,PROJ_BLKS): proj = X @ W via bf16 MFMA 16x16x32.
//  blocks [PROJ_BLKS,..): edge partition into 196 coarse bins (src>>8):
//    LDS histogram + 196 global returning atomics per block + packed stores.
// ---------------------------------------------------------------------------
__global__ __launch_bounds__(256) void combo_kernel(
    const float* __restrict__ X, const float* __restrict__ W,
    const float* __restrict__ att, const int* __restrict__ ei,
    ushort* __restrict__ projT, float* __restrict__ s_src, float* __restrict__ s_tgt,
    int* __restrict__ bin_cursor, unsigned* __restrict__ slab)
{
    __shared__ ushort Wt[128 * WSTR];   // 36.9 KB (partition blocks alias it)

    const int tid = threadIdx.x;

    if (blockIdx.x >= PROJ_BLKS) {
        // ---------------- partition part: 2048 edges per block -----------
        int* cnt   = (int*)Wt;          // 196 ints (aliased onto Wt storage)
        int* gbase = cnt + 256;         // 196 ints

        for (int t = tid; t < NBIN; t += 256) cnt[t] = 0;
        __syncthreads();

        const int ebase = (blockIdx.x - PROJ_BLKS) * 2048;
        unsigned srcv[8], tgtv[8];
        int rank[8];
#pragma unroll
        for (int i = 0; i < 8; ++i) {
            int e = ebase + i * 256 + tid;
            bool ok = e < N_EDGES;
            srcv[i] = ok ? (unsigned)ei[e] : 0u;
            tgtv[i] = ok ? (unsigned)ei[N_EDGES + e] : 0u;
            rank[i] = ok ? atomicAdd(&cnt[srcv[i] >> 8], 1) : -1;
        }
        __syncthreads();

        for (int t = tid; t < NBIN; t += 256)
            gbase[t] = atomicAdd(&bin_cursor[t], cnt[t]);   // 196/block global
        __syncthreads();

#pragma unroll
        for (int i = 0; i < 8; ++i) {
            if (rank[i] >= 0) {
                int bin = srcv[i] >> 8;
                int p = gbase[bin] + rank[i];
                if (p < BINCAP)
                    slab[bin * BINCAP + p] = (tgtv[i] << 16) | (srcv[i] & 255u);
            }
        }
        return;
    }

    // ------------------------- proj part ---------------------------------
    for (int idx = tid; idx < 64 * 128; idx += 256) {
        int kp = idx >> 7;
        int c  = idx & 127;
        float w0 = W[(2 * kp) * PROJ_DIM + c];
        float w1 = W[(2 * kp + 1) * PROJ_DIM + c];
        unsigned pr = (unsigned)f32_to_bf16(w0) | ((unsigned)f32_to_bf16(w1) << 16);
        *(unsigned*)&Wt[c * WSTR + 2 * kp] = pr;
    }
    __syncthreads();

    const int wv   = tid >> 6;
    const int lane = tid & 63;
    const int m = lane & 15;
    const int q = lane >> 4;
    const int rbase = blockIdx.x * 128;

    int arow0 = rbase + wv * 32 + m;
    int arow1 = arow0 + 16;
    arow0 = (arow0 < N_NODES) ? arow0 : N_NODES - 1;
    arow1 = (arow1 < N_NODES) ? arow1 : N_NODES - 1;
    const long long xb0 = (long long)arow0 * IN_DIM;
    const long long xb1 = (long long)arow1 * IN_DIM;

    f32x4 acc[2][8];
#pragma unroll
    for (int rt = 0; rt < 2; ++rt)
#pragma unroll
        for (int ct = 0; ct < 8; ++ct) acc[rt][ct] = (f32x4){0.f, 0.f, 0.f, 0.f};

#pragma unroll
    for (int ks = 0; ks < 4; ++ks) {
        const int k0 = ks * 32 + q * 8;
        float4 a0lo = *(const float4*)&X[xb0 + k0];
        float4 a0hi = *(const float4*)&X[xb0 + k0 + 4];
        float4 a1lo = *(const float4*)&X[xb1 + k0];
        float4 a1hi = *(const float4*)&X[xb1 + k0 + 4];
        bf16x8 afrag0 = cvt8(a0lo, a0hi);
        bf16x8 afrag1 = cvt8(a1lo, a1hi);
#pragma unroll
        for (int ct = 0; ct < 8; ++ct) {
            bf16x8 bfrag = *(const bf16x8*)&Wt[(ct * 16 + m) * WSTR + k0];
            acc[0][ct] = __builtin_amdgcn_mfma_f32_16x16x32_bf16(afrag0, bfrag, acc[0][ct], 0, 0, 0);
            acc[1][ct] = __builtin_amdgcn_mfma_f32_16x16x32_bf16(afrag1, bfrag, acc[1][ct], 0, 0, 0);
        }
    }

    const float as_lo = att[m],      as_hi = att[m + 16];
    const float at_lo = att[32 + m], at_hi = att[48 + m];

#pragma unroll
    for (int rt = 0; rt < 2; ++rt) {
        const int rowb = rbase + wv * 32 + rt * 16 + q * 4;
#pragma unroll
        for (int r = 0; r < 4; ++r) {
            const int row = rowb + r;
            float cl[4], ch[4];
#pragma unroll
            for (int h = 0; h < 4; ++h) {
                cl[h] = acc[rt][2 * h][r];
                ch[h] = acc[rt][2 * h + 1][r];
            }
            if (row < N_NODES) {
                ushort4 plo, phi;
                plo.x = f32_to_bf16(cl[0]); plo.y = f32_to_bf16(cl[1]);
                plo.z = f32_to_bf16(cl[2]); plo.w = f32_to_bf16(cl[3]);
                phi.x = f32_to_bf16(ch[0]); phi.y = f32_to_bf16(ch[1]);
                phi.z = f32_to_bf16(ch[2]); phi.w = f32_to_bf16(ch[3]);
                *(ushort4*)&projT[(long long)row * PROJ_DIM + m * 4] = plo;
                *(ushort4*)&projT[(long long)row * PROJ_DIM + (m + 16) * 4] = phi;
            }
            float ps[4], pt[4];
#pragma unroll
            for (int h = 0; h < 4; ++h) {
                ps[h] = cl[h] * as_lo + ch[h] * as_hi;
                pt[h] = cl[h] * at_lo + ch[h] * at_hi;
            }
#pragma unroll
            for (int off = 8; off > 0; off >>= 1) {
#pragma unroll
                for (int h = 0; h < 4; ++h) {
                    ps[h] += __shfl_down(ps[h], off, 16);
                    pt[h] += __shfl_down(pt[h], off, 16);
                }
            }
            if (m == 0 && row < N_NODES) {
                *(float4*)&s_src[row * N_HEADS] = make_float4(ps[0], ps[1], ps[2], ps[3]);
                *(float4*)&s_tgt[row * N_HEADS] = make_float4(pt[0], pt[1], pt[2], pt[3]);
            }
        }
    }
}

// ---------------------------------------------------------------------------
// K2: binsort (unchanged from R10). One block per bin; LDS-only atomics,
// scan, LDS scatter, coalesced CSR dump. Zero global atomics.
// ---------------------------------------------------------------------------
__global__ __launch_bounds__(256) void binsort_kernel(
    const unsigned* __restrict__ slab, const int* __restrict__ bin_cursor,
    ushort* __restrict__ csr, int* __restrict__ offs, int* __restrict__ deg)
{
    __shared__ int cnt2[256];
    __shared__ int pref[256];
    __shared__ int ex[256];
    __shared__ ushort stgt[BINCAP];    // 10 KB

    const int b = blockIdx.x;
    const int t = threadIdx.x;
    int n_e = bin_cursor[b];
    n_e = (n_e < BINCAP) ? n_e : BINCAP;

    cnt2[t] = 0;
    __syncthreads();

    unsigned pk[20];                   // (tgt<<16)|(rank<<8)|node8
    int npk = 0;
    for (int i = t; i < n_e; i += 256) {
        unsigned v = slab[b * BINCAP + i];
        int node8 = v & 255u;
        int r = atomicAdd(&cnt2[node8], 1);
        r = (r < 255) ? r : 255;
        pk[npk++] = (v & 0xFFFF0000u) | ((unsigned)r << 8) | (unsigned)node8;
    }
    __syncthreads();

    pref[t] = cnt2[t];
    __syncthreads();
    for (int off = 1; off < 256; off <<= 1) {
        int x = (t >= off) ? pref[t - off] : 0;
        __syncthreads();
        pref[t] += x;
        __syncthreads();
    }
    ex[t] = pref[t] - cnt2[t];
    __syncthreads();

    for (int j = 0; j < npk; ++j) {
        unsigned v = pk[j];
        int lpos = ex[v & 255u] + (int)((v >> 8) & 255u);
        if (lpos < BINCAP) stgt[lpos] = (ushort)(v >> 16);
    }
    __syncthreads();

    for (int i = t; i < n_e; i += 256) csr[b * BINCAP + i] = stgt[i];
    int node = b * 256 + t;
    if (node < N_NODES) {
        offs[node] = b * BINCAP + ex[t];
        deg[node]  = cnt2[t];
    }
}

// ---------------------------------------------------------------------------
// K3: gather v2 — barrier-free, LDS-free. One WAVE per node.
//   Prep: lane=edge softmax kept in registers. Main: edge data via __shfl
//   broadcasts. ALL cross-lane shuffles are executed UNconditionally (full
//   EXEC) — ds_bpermute from an EXEC-inactive source lane is undefined, which
//   was R11's correctness bug. Predication selects on the RESULT only.
// ---------------------------------------------------------------------------
__global__ __launch_bounds__(256) void gather_kernel(
    const int* __restrict__ deg, const int* __restrict__ offs,
    const ushort* __restrict__ csr,
    const float* __restrict__ s_src, const float* __restrict__ s_tgt,
    const ushort* __restrict__ projT, float* __restrict__ out)
{
    const int wv   = threadIdx.x >> 6;
    const int lane = threadIdx.x & 63;
    const int node = blockIdx.x * 4 + wv;  // N_NODES = 12500*4

    int n = deg[node];
    n = (n < MAXDEG) ? n : MAXDEG;
    const int o = offs[node];

    int mytgt = 0, myA01 = 0, myA23 = 0;
    if (lane < n) {
        int tgt = csr[o + lane];                            // coalesced ushort
        float4 ss = *(const float4*)&s_src[node * N_HEADS]; // wave-uniform
        float4 st = *(const float4*)&s_tgt[tgt * N_HEADS];  // parallel gather

        float sc[4] = { ss.x + st.x, ss.y + st.y, ss.z + st.z, ss.w + st.w };
        float mx = -1e30f;
#pragma unroll
        for (int h = 0; h < 4; ++h) {
            sc[h] = (sc[h] > 0.0f) ? sc[h] : 0.01f * sc[h];  // leaky_relu
            mx = fmaxf(mx, sc[h]);
        }
        float sum = 0.0f;
#pragma unroll
        for (int h = 0; h < 4; ++h) {
            sc[h] = __expf(sc[h] - mx);
            sum += sc[h];
        }
        float inv = 0.25f / sum;     // softmax normalize * head-mean

        h2 a01, a23;
        a01.x = (_Float16)(sc[0] * inv);
        a01.y = (_Float16)(sc[1] * inv);
        a23.x = (_Float16)(sc[2] * inv);
        a23.y = (_Float16)(sc[3] * inv);
        mytgt = tgt;
        myA01 = __builtin_bit_cast(int, a01);
        myA23 = __builtin_bit_cast(int, a23);
    }
    // no barrier: producers and consumers are the same wave

    const int d    = lane & 31;
    const int half = lane >> 5;

    float acc0 = 0.0f, acc1 = 0.0f, acc2 = 0.0f, acc3 = 0.0f;
    int j = 0;

    // 16 edges per wave pass (8 per half): shuffle-broadcast edge data,
    // 8 outstanding projT gathers per lane. All lanes active -> shuffles safe.
    for (; j + 15 < n; j += 16) {
        int tg[8], ea[8], eb[8];
#pragma unroll
        for (int u = 0; u < 8; ++u) {
            int sl = j + 2 * u + half;
            tg[u] = __shfl(mytgt, sl);
            ea[u] = __shfl(myA01, sl);
            eb[u] = __shfl(myA23, sl);
        }
        ushort4 p[8];
#pragma unroll
        for (int u = 0; u < 8; ++u)
            p[u] = *(const ushort4*)&projT[(long long)tg[u] * PROJ_DIM + d * 4];
#pragma unroll
        for (int u = 0; u < 8; ++u) {
            h2 a = __builtin_bit_cast(h2, ea[u]);
            h2 b = __builtin_bit_cast(h2, eb[u]);
            float* accp = (u & 1) ? ((u & 2) ? &acc3 : &acc1)
                                  : ((u & 2) ? &acc2 : &acc0);
            float tt = *accp;
            tt = fmaf((float)a.x, bf16_to_f32(p[u].x), tt);
            tt = fmaf((float)a.y, bf16_to_f32(p[u].y), tt);
            tt = fmaf((float)b.x, bf16_to_f32(p[u].z), tt);
            tt = fmaf((float)b.y, bf16_to_f32(p[u].w), tt);
            *accp = tt;
        }
    }
    // remainder, 2 edges/pass: shuffles UNCONDITIONAL (full exec), then
    // zero the alphas for out-of-range slots.
    for (; j < n; j += 2) {
        int sl = j + half;
        bool ok = sl < n;
        int slc = ok ? sl : 0;
        int tg = __shfl(mytgt, slc);
        int ea = __shfl(myA01, slc);
        int eb = __shfl(myA23, slc);
        if (!ok) { ea = 0; eb = 0; }
        ushort4 pv = *(const ushort4*)&projT[(long long)tg * PROJ_DIM + d * 4];
        h2 a = __builtin_bit_cast(h2, ea);
        h2 b = __builtin_bit_cast(h2, eb);
        acc0 = fmaf((float)a.x, bf16_to_f32(pv.x), acc0);
        acc0 = fmaf((float)a.y, bf16_to_f32(pv.y), acc0);
        acc0 = fmaf((float)b.x, bf16_to_f32(pv.z), acc0);
        acc0 = fmaf((float)b.y, bf16_to_f32(pv.w), acc0);
    }

    float acc = (acc0 + acc1) + (acc2 + acc3);
    acc += __shfl_down(acc, 32);      // combine the two halves (width 64)
    if (lane < 32) out[node * OUT_DIM + d] = acc;
}

extern "C" void kernel_launch(void* const* d_in, const int* in_sizes, int n_in,
                              void* d_out, int out_size, void* d_ws, size_t ws_size,
                              hipStream_t stream) {
    const float* X   = (const float*)d_in[0];
    const int*   ei  = (const int*)d_in[1];
    const float* W   = (const float*)d_in[2];
    const float* att = (const float*)d_in[3];
    float* out = (float*)d_out;

    // workspace layout, total ~20.8 MB
    char* p = (char*)d_ws;
    ushort* projT   = (ushort*)p;   p += (size_t)N_NODES * PROJ_DIM * 2;  // 12.8 MB
    float* s_src    = (float*)p;    p += (size_t)N_NODES * N_HEADS * 4;   // 0.8 MB
    float* s_tgt    = (float*)p;    p += (size_t)N_NODES * N_HEADS * 4;   // 0.8 MB
    unsigned* slab  = (unsigned*)p; p += (size_t)NBIN * BINCAP * 4;       // 3.92 MB
    ushort* csr     = (ushort*)p;   p += (size_t)NBIN * BINCAP * 2;       // 1.96 MB
    int* offs       = (int*)p;      p += (size_t)N_NODES * 4;             // 0.2 MB
    int* deg        = (int*)p;      p += (size_t)N_NODES * 4;             // 0.2 MB
    int* bin_cursor = (int*)p;      p += 256 * 4;

    (void)hipMemsetAsync(bin_cursor, 0, 256 * sizeof(int), stream);

    combo_kernel<<<TOTAL_BLKS, 256, 0, stream>>>(
        X, W, att, ei, projT, s_src, s_tgt, bin_cursor, slab);

    binsort_kernel<<<NBIN, 256, 0, stream>>>(slab, bin_cursor, csr, offs, deg);

    gather_kernel<<<N_NODES / 4, 256, 0, stream>>>(
        deg, offs, csr, s_src, s_tgt, projT, out);
}